// Round 4
// baseline (86.063 us; speedup 1.0000x reference)
//
#include <hip/hip_runtime.h>

// FEM stiffness matrix assembly (negated), single-write-pass version, v2.
//
// out = -M (dense N x N, N = 9216). Mesh stencil is narrow-banded
// (|col-row| <= 97 for the structured 96x96 mesh): accumulate per-row bands
// in workspace, then stream the dense output in ONE pass.
//
// R3 -> R4 changes:
//  - scatter: 9x parallelism (thread per (triangle, contribution), q = blockIdx.y,
//    block-uniform switch instead of runtime-indexed arrays)
//  - writer: no LDS, no nontemporal stores, plain f32x4 stores (mimic
//    fillBufferAligned which hits 86% peak); band read direct from global.

#define BAND 256
#define HALF 128

typedef float f32x4 __attribute__((ext_vector_type(4)));

__device__ __forceinline__ void tri_values(const float* __restrict__ pts,
                                           const int* __restrict__ cmap,
                                           int t, int nd[3], float M[6]) {
    int ni = cmap[3 * t + 0];
    int nj = cmap[3 * t + 1];
    int nk = cmap[3 * t + 2];
    nd[0] = ni; nd[1] = nj; nd[2] = nk;

    float x0 = pts[2 * ni + 0], y0 = pts[2 * ni + 1];
    float x1 = pts[2 * nj + 0], y1 = pts[2 * nj + 1];
    float x2 = pts[2 * nk + 0], y2 = pts[2 * nk + 1];

    float det = (x1 - x0) * (y2 - y0) - (x2 - x0) * (y1 - y0);
    float area = 0.5f * fabsf(det);
    float inv = 1.0f / det;

    float gix = (y1 - y2) * inv, giy = (x2 - x1) * inv;
    float gjx = (y2 - y0) * inv, gjy = (x0 - x2) * inv;
    float gkx = (y0 - y1) * inv, gky = (x1 - x0) * inv;

    M[0] = (gix * gix + giy * giy) * area;  // ii
    M[1] = (gjx * gjx + gjy * gjy) * area;  // jj
    M[2] = (gkx * gkx + gky * gky) * area;  // kk
    M[3] = (gix * gjx + giy * gjy) * area;  // ij
    M[4] = (gjx * gkx + gjy * gky) * area;  // jk
    M[5] = (gkx * gix + gky * giy) * area;  // ki
}

// One thread per (triangle, contribution q). q = blockIdx.y in [0,9):
// block-uniform, so the switch below is non-divergent.
__global__ void scatter_band_kernel(const float* __restrict__ pts,
                                    const int* __restrict__ cmap,
                                    float* __restrict__ band,
                                    int T) {
    int t = blockIdx.x * blockDim.x + threadIdx.x;
    if (t >= T) return;
    int q = blockIdx.y;

    int nd[3]; float M[6];
    tri_values(pts, cmap, t, nd, M);

    int row, col; float val;
    switch (q) {
        case 0: row = nd[0]; col = nd[0]; val = M[0]; break;  // ii
        case 1: row = nd[1]; col = nd[1]; val = M[1]; break;  // jj
        case 2: row = nd[2]; col = nd[2]; val = M[2]; break;  // kk
        case 3: row = nd[0]; col = nd[1]; val = M[3]; break;  // ij
        case 4: row = nd[1]; col = nd[0]; val = M[3]; break;  // ji
        case 5: row = nd[1]; col = nd[2]; val = M[4]; break;  // jk
        case 6: row = nd[2]; col = nd[1]; val = M[4]; break;  // kj
        case 7: row = nd[2]; col = nd[0]; val = M[5]; break;  // ki
        default: row = nd[0]; col = nd[2]; val = M[5]; break; // ik
    }

    int off = col - row + HALF;
    if ((unsigned)off < BAND) {  // always true for the structured mesh
        atomicAdd(&band[(size_t)row * BAND + off], -val);
    }
}

// One block per row: stream the dense row with plain f32x4 stores; band
// values read straight from global (coalesced, L2-resident, rare path).
__global__ void __launch_bounds__(256) write_rows_kernel(const float* __restrict__ band,
                                                         float* __restrict__ out,
                                                         int N) {
    int r = blockIdx.x;
    const float* __restrict__ brow = band + (size_t)r * BAND;
    f32x4* __restrict__ orow = (f32x4*)(out + (size_t)r * N);
    int nvec = N >> 2;
    int lo = r - HALF;       // first col possibly in band
    int hi = r + HALF - 1;   // last col possibly in band

    for (int v = threadIdx.x; v < nvec; v += 256) {
        int c0 = v << 2;
        f32x4 val = (f32x4){0.f, 0.f, 0.f, 0.f};
        if (c0 + 3 >= lo && c0 <= hi) {
            #pragma unroll
            for (int e = 0; e < 4; ++e) {
                int off = c0 + e - r + HALF;
                if ((unsigned)off < BAND) val[e] = brow[off];
            }
        }
        orow[v] = val;
    }
    // Tail (N % 4 != 0) — not hit for N = 9216.
    for (int c = (nvec << 2) + threadIdx.x; c < N; c += 256) {
        int off = c - r + HALF;
        out[(size_t)r * N + c] = ((unsigned)off < BAND) ? brow[off] : 0.f;
    }
}

// ---- Fallback path (ws too small): memset + atomic scatter ----
__global__ void fem_assemble_atomic_kernel(const float* __restrict__ pts,
                                           const int* __restrict__ cmap,
                                           float* __restrict__ out,
                                           int T, int N) {
    int t = blockIdx.x * blockDim.x + threadIdx.x;
    if (t >= T) return;
    int nd[3]; float M[6];
    tri_values(pts, cmap, t, nd, M);
    size_t Ns = (size_t)N;
    atomicAdd(&out[(size_t)nd[0] * Ns + nd[0]], -M[0]);
    atomicAdd(&out[(size_t)nd[1] * Ns + nd[1]], -M[1]);
    atomicAdd(&out[(size_t)nd[2] * Ns + nd[2]], -M[2]);
    atomicAdd(&out[(size_t)nd[0] * Ns + nd[1]], -M[3]);
    atomicAdd(&out[(size_t)nd[1] * Ns + nd[0]], -M[3]);
    atomicAdd(&out[(size_t)nd[1] * Ns + nd[2]], -M[4]);
    atomicAdd(&out[(size_t)nd[2] * Ns + nd[1]], -M[4]);
    atomicAdd(&out[(size_t)nd[2] * Ns + nd[0]], -M[5]);
    atomicAdd(&out[(size_t)nd[0] * Ns + nd[2]], -M[5]);
}

extern "C" void kernel_launch(void* const* d_in, const int* in_sizes, int n_in,
                              void* d_out, int out_size, void* d_ws, size_t ws_size,
                              hipStream_t stream) {
    const float* pts = (const float*)d_in[0];   // (N, 2) float32
    const int* cmap = (const int*)d_in[1];      // (T, 3) int
    int N = in_sizes[0] / 2;                    // 9216 nodes
    int T = in_sizes[1] / 3;                    // 18050 triangles
    float* out = (float*)d_out;

    size_t band_bytes = (size_t)N * BAND * sizeof(float);  // 9.4 MB

    if (ws_size >= band_bytes) {
        float* band = (float*)d_ws;
        (void)hipMemsetAsync(band, 0, band_bytes, stream);
        dim3 sgrid((T + 255) / 256, 9);
        scatter_band_kernel<<<sgrid, 256, 0, stream>>>(pts, cmap, band, T);
        write_rows_kernel<<<N, 256, 0, stream>>>(band, out, N);
    } else {
        (void)hipMemsetAsync(d_out, 0, (size_t)out_size * sizeof(float), stream);
        fem_assemble_atomic_kernel<<<(T + 255) / 256, 256, 0, stream>>>(pts, cmap, out, T, N);
    }
}

// Round 5
// 68.264 us; speedup vs baseline: 1.2607x; 1.2607x over previous
//
#include <hip/hip_runtime.h>

// FEM stiffness matrix assembly (negated): out = -M, dense N x N (N = 9216).
//
// Structure (R5): the 340 MB dense-zero cost is irreducible and the rocclr
// fill kernel (hipMemsetAsync) is the fastest zeroing we've measured
// (>=6.2 TB/s); custom single-pass writers plateaued at ~4.4 TB/s (R3/R4).
// So: memset the output, then a 9-way-parallel atomic scatter directly into
// it (one thread per (triangle, contribution); blockIdx.y = contribution id,
// block-uniform switch -> no divergence, no runtime-indexed local arrays).

__device__ __forceinline__ void tri_values(const float* __restrict__ pts,
                                           const int* __restrict__ cmap,
                                           int t, int nd[3], float M[6]) {
    int ni = cmap[3 * t + 0];
    int nj = cmap[3 * t + 1];
    int nk = cmap[3 * t + 2];
    nd[0] = ni; nd[1] = nj; nd[2] = nk;

    float x0 = pts[2 * ni + 0], y0 = pts[2 * ni + 1];
    float x1 = pts[2 * nj + 0], y1 = pts[2 * nj + 1];
    float x2 = pts[2 * nk + 0], y2 = pts[2 * nk + 1];

    float det = (x1 - x0) * (y2 - y0) - (x2 - x0) * (y1 - y0);
    float area = 0.5f * fabsf(det);
    float inv = 1.0f / det;

    float gix = (y1 - y2) * inv, giy = (x2 - x1) * inv;
    float gjx = (y2 - y0) * inv, gjy = (x0 - x2) * inv;
    float gkx = (y0 - y1) * inv, gky = (x1 - x0) * inv;

    M[0] = (gix * gix + giy * giy) * area;  // ii
    M[1] = (gjx * gjx + gjy * gjy) * area;  // jj
    M[2] = (gkx * gkx + gky * gky) * area;  // kk
    M[3] = (gix * gjx + giy * gjy) * area;  // ij
    M[4] = (gjx * gkx + gjy * gky) * area;  // jk
    M[5] = (gkx * gix + gky * giy) * area;  // ki
}

// One thread per (triangle, contribution q). q = blockIdx.y in [0,9):
// block-uniform switch, atomics straight into the dense output.
__global__ void scatter_out_kernel(const float* __restrict__ pts,
                                   const int* __restrict__ cmap,
                                   float* __restrict__ out,
                                   int T, int N) {
    int t = blockIdx.x * blockDim.x + threadIdx.x;
    if (t >= T) return;
    int q = blockIdx.y;

    int nd[3]; float M[6];
    tri_values(pts, cmap, t, nd, M);

    int row, col; float val;
    switch (q) {
        case 0: row = nd[0]; col = nd[0]; val = M[0]; break;  // ii
        case 1: row = nd[1]; col = nd[1]; val = M[1]; break;  // jj
        case 2: row = nd[2]; col = nd[2]; val = M[2]; break;  // kk
        case 3: row = nd[0]; col = nd[1]; val = M[3]; break;  // ij
        case 4: row = nd[1]; col = nd[0]; val = M[3]; break;  // ji
        case 5: row = nd[1]; col = nd[2]; val = M[4]; break;  // jk
        case 6: row = nd[2]; col = nd[1]; val = M[4]; break;  // kj
        case 7: row = nd[2]; col = nd[0]; val = M[5]; break;  // ki
        default: row = nd[0]; col = nd[2]; val = M[5]; break; // ik
    }

    atomicAdd(&out[(size_t)row * N + col], -val);
}

extern "C" void kernel_launch(void* const* d_in, const int* in_sizes, int n_in,
                              void* d_out, int out_size, void* d_ws, size_t ws_size,
                              hipStream_t stream) {
    const float* pts = (const float*)d_in[0];   // (N, 2) float32
    const int* cmap = (const int*)d_in[1];      // (T, 3) int
    int N = in_sizes[0] / 2;                    // 9216 nodes
    int T = in_sizes[1] / 3;                    // 18050 triangles
    float* out = (float*)d_out;

    // Zero the dense output (rocclr fill kernel, ~6.4 TB/s). Required every
    // call: atomics below accumulate and the harness doesn't re-poison
    // between graph replays.
    (void)hipMemsetAsync(d_out, 0, (size_t)out_size * sizeof(float), stream);

    dim3 sgrid((T + 255) / 256, 9);
    scatter_out_kernel<<<sgrid, 256, 0, stream>>>(pts, cmap, out, T, N);
}